// Round 1
// baseline (783.348 us; speedup 1.0000x reference)
//
#include <hip/hip_runtime.h>

#define N_NODES 25600
#define F_IN 400
#define D0 404
#define HDIM 128
#define NE 512000
#define NB 64
#define NPG 400
#define BN_EPS 1e-5f

// ---------------- CSR build ----------------

__global__ void zero_i32(int* p, int n) {
    int i = blockIdx.x * 256 + threadIdx.x;
    if (i < n) p[i] = 0;
}

__global__ void count_edges(const int* __restrict__ dst, int* __restrict__ cnt) {
    int e = blockIdx.x * 256 + threadIdx.x;
    if (e < NE) atomicAdd(&cnt[dst[e]], 1);
}

// 25600 = 1024 * 25; single-block exclusive scan
__global__ __launch_bounds__(1024) void scan_csr(const int* __restrict__ cnt,
                                                 int* __restrict__ off,
                                                 int* __restrict__ cur) {
    __shared__ int lds[1024];
    int tid = threadIdx.x;
    int base = tid * 25;
    int loc[25];
    int s = 0;
#pragma unroll
    for (int j = 0; j < 25; ++j) { loc[j] = s; s += cnt[base + j]; }
    lds[tid] = s;
    __syncthreads();
    // Hillis-Steele inclusive scan
    for (int d = 1; d < 1024; d <<= 1) {
        int t2 = (tid >= d) ? lds[tid - d] : 0;
        __syncthreads();
        lds[tid] += t2;
        __syncthreads();
    }
    int incl = lds[tid];
    int excl = incl - s;
#pragma unroll
    for (int j = 0; j < 25; ++j) {
        int v = excl + loc[j];
        off[base + j] = v;
        cur[base + j] = v;
    }
    if (tid == 1023) off[N_NODES] = incl;
}

__global__ void scatter_edges(const int* __restrict__ src, const int* __restrict__ dst,
                              int* __restrict__ cur, int* __restrict__ esrc) {
    int e = blockIdx.x * 256 + threadIdx.x;
    if (e < NE) {
        int d = dst[e];
        int pos = atomicAdd(&cur[d], 1);
        esrc[pos] = src[e];
    }
}

// ---------------- feature embed: h0 = [x | ge[gid] | he[i%2]] ----------------

__global__ __launch_bounds__(128) void embed(const float* __restrict__ x,
                                             const int* __restrict__ gid,
                                             const float* __restrict__ ge,
                                             const float* __restrict__ he,
                                             float* __restrict__ h0) {
    int i = blockIdx.x;
    const float* xr = x + (size_t)i * F_IN;
    float* hr = h0 + (size_t)i * D0;
    for (int j = threadIdx.x; j < F_IN; j += 128) hr[j] = xr[j];
    if (threadIdx.x == 0) {
        int g = gid[i];
        hr[400] = ge[g * 2 + 0];
        hr[401] = ge[g * 2 + 1];
        int hm = i & 1;
        hr[402] = he[hm * 2 + 0];
        hr[403] = he[hm * 2 + 1];
    }
}

// ---------------- GIN aggregation: z[i] = h[i] + sum_{e: dst=i} h[src_e] ----------------

__global__ __launch_bounds__(128) void aggregate(const float* __restrict__ h,
                                                 const int* __restrict__ off,
                                                 const int* __restrict__ esrc,
                                                 float* __restrict__ z, int D) {
    int i = blockIdx.x;
    int t = threadIdx.x;
    int e0 = off[i], e1 = off[i + 1];
    float acc[4] = {0.f, 0.f, 0.f, 0.f};
    const float* hi = h + (size_t)i * D;
    int nf = 0;
    for (int f = t; f < D; f += 128) { acc[nf] = hi[f]; ++nf; }
    __shared__ int se[128];
    for (int eb = e0; eb < e1; eb += 128) {
        int ne = min(128, e1 - eb);
        __syncthreads();
        if (t < ne) se[t] = esrc[eb + t];
        __syncthreads();
        for (int k = 0; k < ne; ++k) {
            const float* hs = h + (size_t)se[k] * D;
            int f = t;
            for (int j = 0; j < nf; ++j, f += 128) acc[j] += hs[f];
        }
    }
    float* zi = z + (size_t)i * D;
    int f = t;
    for (int j = 0; j < nf; ++j, f += 128) zi[f] = acc[j];
}

// ---------------- GEMM1: T = Z @ W + b, plus per-block column sum/sumsq partials ----------------
// grid = 400 blocks (64 rows each), 256 threads; thread = (tx 0..31 -> 4 cols, ty 0..7 -> 8 rows)

__global__ __launch_bounds__(256) void gemm_bn_stats(const float* __restrict__ Z,
                                                     const float* __restrict__ W,
                                                     const float* __restrict__ bias,
                                                     float* __restrict__ T,
                                                     float* __restrict__ psum,
                                                     float* __restrict__ psq, int K) {
    __shared__ float Zs[64][33];
    __shared__ float Ws[32][128];
    __shared__ float rs[8][128];
    __shared__ float rq[8][128];
    int tid = threadIdx.x;
    int tx = tid & 31;
    int ty = tid >> 5;
    int row0 = blockIdx.x * 64;
    float acc[8][4];
#pragma unroll
    for (int r = 0; r < 8; ++r)
#pragma unroll
        for (int c = 0; c < 4; ++c) acc[r][c] = 0.f;

    for (int k0 = 0; k0 < K; k0 += 32) {
#pragma unroll
        for (int p = 0; p < 8; ++p) {
            int lin = p * 256 + tid;
            int r = lin >> 5, kk = lin & 31;
            int kg = k0 + kk;
            Zs[r][kk] = (kg < K) ? Z[(size_t)(row0 + r) * K + kg] : 0.f;
        }
#pragma unroll
        for (int p = 0; p < 16; ++p) {
            int lin = p * 256 + tid;
            int kr = lin >> 7, c = lin & 127;
            int kg = k0 + kr;
            Ws[kr][c] = (kg < K) ? W[(size_t)kg * 128 + c] : 0.f;
        }
        __syncthreads();
#pragma unroll
        for (int kk = 0; kk < 32; ++kk) {
            float4 w = *(const float4*)&Ws[kk][tx * 4];
#pragma unroll
            for (int r = 0; r < 8; ++r) {
                float zz = Zs[ty * 8 + r][kk];
                acc[r][0] += zz * w.x;
                acc[r][1] += zz * w.y;
                acc[r][2] += zz * w.z;
                acc[r][3] += zz * w.w;
            }
        }
        __syncthreads();
    }

    float4 bv = *(const float4*)&bias[tx * 4];
    float s[4] = {0.f, 0.f, 0.f, 0.f}, q[4] = {0.f, 0.f, 0.f, 0.f};
#pragma unroll
    for (int r = 0; r < 8; ++r) {
        int row = row0 + ty * 8 + r;
        float v0 = acc[r][0] + bv.x, v1 = acc[r][1] + bv.y;
        float v2 = acc[r][2] + bv.z, v3 = acc[r][3] + bv.w;
        float4 o = {v0, v1, v2, v3};
        *(float4*)&T[(size_t)row * 128 + tx * 4] = o;
        s[0] += v0; s[1] += v1; s[2] += v2; s[3] += v3;
        q[0] += v0 * v0; q[1] += v1 * v1; q[2] += v2 * v2; q[3] += v3 * v3;
    }
#pragma unroll
    for (int c = 0; c < 4; ++c) { rs[ty][tx * 4 + c] = s[c]; rq[ty][tx * 4 + c] = q[c]; }
    __syncthreads();
    if (tid < 128) {
        float S = 0.f, Q = 0.f;
#pragma unroll
        for (int j = 0; j < 8; ++j) { S += rs[j][tid]; Q += rq[j][tid]; }
        psum[blockIdx.x * 128 + tid] = S;
        psq[blockIdx.x * 128 + tid] = Q;
    }
}

// ---------------- BN coefficients: a = g*rsqrt(var+eps), c = be - a*mu ----------------

__global__ __launch_bounds__(1024) void bn_coef(const float* __restrict__ psum,
                                                const float* __restrict__ psq,
                                                const float* __restrict__ g,
                                                const float* __restrict__ be,
                                                float* __restrict__ coef) {
    __shared__ float ss[8][128], sq[8][128];
    int c = threadIdx.x & 127;
    int p = threadIdx.x >> 7;
    float s = 0.f, q = 0.f;
    for (int b = p; b < 400; b += 8) { s += psum[b * 128 + c]; q += psq[b * 128 + c]; }
    ss[p][c] = s; sq[p][c] = q;
    __syncthreads();
    if (p == 0) {
#pragma unroll
        for (int j = 1; j < 8; ++j) { s += ss[j][c]; q += sq[j][c]; }
        float invn = 1.0f / (float)N_NODES;
        float mu = s * invn;
        float var = q * invn - mu * mu;
        float a = g[c] * rsqrtf(var + BN_EPS);
        coef[c] = a;
        coef[128 + c] = be[c] - a * mu;
    }
}

// ---------------- GEMM2: Hout = relu( relu(a*T+c) @ W + b ) ----------------

__global__ __launch_bounds__(256) void gemm_relu(const float* __restrict__ T,
                                                 const float* __restrict__ coef,
                                                 const float* __restrict__ W,
                                                 const float* __restrict__ bias,
                                                 float* __restrict__ Hout) {
    __shared__ float Zs[64][33];
    __shared__ float Ws[32][128];
    int tid = threadIdx.x;
    int tx = tid & 31;
    int ty = tid >> 5;
    int row0 = blockIdx.x * 64;
    float acc[8][4];
#pragma unroll
    for (int r = 0; r < 8; ++r)
#pragma unroll
        for (int c = 0; c < 4; ++c) acc[r][c] = 0.f;

    for (int k0 = 0; k0 < 128; k0 += 32) {
#pragma unroll
        for (int p = 0; p < 8; ++p) {
            int lin = p * 256 + tid;
            int r = lin >> 5, kk = lin & 31;
            int kg = k0 + kk;
            float raw = T[(size_t)(row0 + r) * 128 + kg];
            Zs[r][kk] = fmaxf(coef[kg] * raw + coef[128 + kg], 0.f);
        }
#pragma unroll
        for (int p = 0; p < 16; ++p) {
            int lin = p * 256 + tid;
            int kr = lin >> 7, c = lin & 127;
            Ws[kr][c] = W[(size_t)(k0 + kr) * 128 + c];
        }
        __syncthreads();
#pragma unroll
        for (int kk = 0; kk < 32; ++kk) {
            float4 w = *(const float4*)&Ws[kk][tx * 4];
#pragma unroll
            for (int r = 0; r < 8; ++r) {
                float zz = Zs[ty * 8 + r][kk];
                acc[r][0] += zz * w.x;
                acc[r][1] += zz * w.y;
                acc[r][2] += zz * w.z;
                acc[r][3] += zz * w.w;
            }
        }
        __syncthreads();
    }

    float4 bv = *(const float4*)&bias[tx * 4];
#pragma unroll
    for (int r = 0; r < 8; ++r) {
        int row = row0 + ty * 8 + r;
        float4 o;
        o.x = fmaxf(acc[r][0] + bv.x, 0.f);
        o.y = fmaxf(acc[r][1] + bv.y, 0.f);
        o.z = fmaxf(acc[r][2] + bv.z, 0.f);
        o.w = fmaxf(acc[r][3] + bv.w, 0.f);
        *(float4*)&Hout[(size_t)row * 128 + tx * 4] = o;
    }
}

// ---------------- head: pool + relu(p@wfa+bfa) @ wfb + bfb ----------------

__global__ __launch_bounds__(128) void head(const float* __restrict__ h,
                                            const float* __restrict__ wfa,
                                            const float* __restrict__ bfa,
                                            const float* __restrict__ wfb,
                                            const float* __restrict__ bfb,
                                            float* __restrict__ out) {
    int g = blockIdx.x;   // 64 graphs
    int f = threadIdx.x;  // 128 features
    const float* hg = h + (size_t)g * NPG * 128;
    float pooled = 0.f;
    for (int n = 0; n < NPG; n += 4) {
        pooled += hg[(n + 0) * 128 + f];
        pooled += hg[(n + 1) * 128 + f];
        pooled += hg[(n + 2) * 128 + f];
        pooled += hg[(n + 3) * 128 + f];
    }
    __shared__ float pl[128];
    pl[f] = pooled;
    __syncthreads();
    float a = bfa[f];
    for (int k = 0; k < 128; ++k) a += pl[k] * wfa[k * 128 + f];
    float p2 = fmaxf(a, 0.f);
    __shared__ float o0[128], o1[128];
    o0[f] = p2 * wfb[f * 2 + 0];
    o1[f] = p2 * wfb[f * 2 + 1];
    __syncthreads();
    if (f == 0) {
        float a0 = bfb[0], a1 = bfb[1];
#pragma unroll
        for (int k = 0; k < 128; ++k) { a0 += o0[k]; a1 += o1[k]; }
        out[g * 2 + 0] = a0;
        out[g * 2 + 1] = a1;
    }
}

// ---------------- launch ----------------

extern "C" void kernel_launch(void* const* d_in, const int* in_sizes, int n_in,
                              void* d_out, int out_size, void* d_ws, size_t ws_size,
                              hipStream_t stream) {
    const float* x   = (const float*)d_in[0];
    const int* ei    = (const int*)d_in[1];      // [2, NE]
    // d_in[2] = batch (implicit: i / 400)
    const int* gid   = (const int*)d_in[3];
    const float* ge  = (const float*)d_in[4];
    const float* he  = (const float*)d_in[5];
    const float* wa[3] = {(const float*)d_in[6],  (const float*)d_in[12], (const float*)d_in[18]};
    const float* ba[3] = {(const float*)d_in[7],  (const float*)d_in[13], (const float*)d_in[19]};
    const float* gg[3] = {(const float*)d_in[8],  (const float*)d_in[14], (const float*)d_in[20]};
    const float* bb_[3]= {(const float*)d_in[9],  (const float*)d_in[15], (const float*)d_in[21]};
    const float* wb[3] = {(const float*)d_in[10], (const float*)d_in[16], (const float*)d_in[22]};
    const float* bbias[3] = {(const float*)d_in[11], (const float*)d_in[17], (const float*)d_in[23]};
    const float* wfa = (const float*)d_in[24];
    const float* bfa = (const float*)d_in[25];
    const float* wfb = (const float*)d_in[26];
    const float* bfb = (const float*)d_in[27];
    float* out = (float*)d_out;

    // workspace layout
    char* ws = (char*)d_ws;
    size_t o = 0;
    auto alloc = [&](size_t bytes) { char* p = ws + o; o += (bytes + 255) & ~(size_t)255; return p; };
    float* h0   = (float*)alloc((size_t)N_NODES * D0 * 4);
    float* z    = (float*)alloc((size_t)N_NODES * D0 * 4);
    float* t    = (float*)alloc((size_t)N_NODES * 128 * 4);
    float* h    = (float*)alloc((size_t)N_NODES * 128 * 4);
    float* psum = (float*)alloc(400 * 128 * 4);
    float* psq  = (float*)alloc(400 * 128 * 4);
    float* coef = (float*)alloc(256 * 4);
    int* cnt    = (int*)alloc(N_NODES * 4);
    int* off    = (int*)alloc((N_NODES + 1) * 4);
    int* cur    = (int*)alloc(N_NODES * 4);
    int* esrc   = (int*)alloc(NE * 4);
    (void)ws_size; (void)in_sizes; (void)n_in; (void)out_size;

    const int* esrc_in = ei;
    const int* edst_in = ei + NE;

    // CSR build
    zero_i32<<<(N_NODES + 255) / 256, 256, 0, stream>>>(cnt, N_NODES);
    count_edges<<<(NE + 255) / 256, 256, 0, stream>>>(edst_in, cnt);
    scan_csr<<<1, 1024, 0, stream>>>(cnt, off, cur);
    scatter_edges<<<(NE + 255) / 256, 256, 0, stream>>>(esrc_in, edst_in, cur, esrc);

    // embed
    embed<<<N_NODES, 128, 0, stream>>>(x, gid, ge, he, h0);

    const float* hin = h0;
    int D = D0;
    for (int L = 0; L < 3; ++L) {
        aggregate<<<N_NODES, 128, 0, stream>>>(hin, off, esrc, z, D);
        gemm_bn_stats<<<400, 256, 0, stream>>>(z, wa[L], ba[L], t, psum, psq, D);
        bn_coef<<<1, 1024, 0, stream>>>(psum, psq, gg[L], bb_[L], coef);
        gemm_relu<<<400, 256, 0, stream>>>(t, coef, wb[L], bbias[L], h);
        hin = h;
        D = 128;
    }

    head<<<NB, 128, 0, stream>>>(h, wfa, bfa, wfb, bfb, out);
}

// Round 4
// 512.661 us; speedup vs baseline: 1.5280x; 1.5280x over previous
//
#include <hip/hip_runtime.h>

#define N_NODES 25600
#define F_IN 400
#define NE 512000
#define NB 64
#define NPG 400
#define EPG 8000
#define BN_EPS 1e-5f

// ---------------- CSR build ----------------

__global__ void zero_i32(int* p, int n) {
    int i = blockIdx.x * 256 + threadIdx.x;
    if (i < n) p[i] = 0;
}

__global__ void count_edges(const int* __restrict__ dst, int* __restrict__ cnt) {
    int e = blockIdx.x * 256 + threadIdx.x;
    if (e < NE) atomicAdd(&cnt[dst[e]], 1);
}

// 25600 = 1024 * 25; single-block exclusive scan
__global__ __launch_bounds__(1024) void scan_csr(const int* __restrict__ cnt,
                                                 int* __restrict__ off,
                                                 int* __restrict__ cur) {
    __shared__ int lds[1024];
    int tid = threadIdx.x;
    int base = tid * 25;
    int loc[25];
    int s = 0;
#pragma unroll
    for (int j = 0; j < 25; ++j) { loc[j] = s; s += cnt[base + j]; }
    lds[tid] = s;
    __syncthreads();
    for (int d = 1; d < 1024; d <<= 1) {
        int t2 = (tid >= d) ? lds[tid - d] : 0;
        __syncthreads();
        lds[tid] += t2;
        __syncthreads();
    }
    int incl = lds[tid];
    int excl = incl - s;
#pragma unroll
    for (int j = 0; j < 25; ++j) {
        int v = excl + loc[j];
        off[base + j] = v;
        cur[base + j] = v;
    }
    if (tid == 1023) off[N_NODES] = incl;
}

__global__ void scatter_edges(const int* __restrict__ src, const int* __restrict__ dst,
                              int* __restrict__ cur, unsigned short* __restrict__ esrc16) {
    int e = blockIdx.x * 256 + threadIdx.x;
    if (e < NE) {
        int d = dst[e];
        int pos = atomicAdd(&cur[d], 1);
        esrc16[pos] = (unsigned short)(src[e] % NPG);  // local index within graph
    }
}

// ---------------- GEMM layer0: T = [x | ge[gid] | he[i%2]] @ W0a  (no bias) ----------------

__global__ __launch_bounds__(256) void gemm_embed(const float* __restrict__ X,
                                                  const int* __restrict__ gid,
                                                  const float* __restrict__ ge,
                                                  const float* __restrict__ he,
                                                  const float* __restrict__ W,
                                                  float* __restrict__ T) {
    __shared__ float Zs[64][33];
    __shared__ float Ws[32][128];
    __shared__ float Wex[4][128];
    int tid = threadIdx.x;
    int tx = tid & 31;
    int ty = tid >> 5;
    int row0 = blockIdx.x * 64;
    float acc[8][4];
#pragma unroll
    for (int r = 0; r < 8; ++r)
#pragma unroll
        for (int c = 0; c < 4; ++c) acc[r][c] = 0.f;

    for (int i = tid; i < 512; i += 256)
        Wex[i >> 7][i & 127] = W[(size_t)(400 + (i >> 7)) * 128 + (i & 127)];

    for (int k0 = 0; k0 < 400; k0 += 32) {
#pragma unroll
        for (int p = 0; p < 8; ++p) {
            int lin = p * 256 + tid;
            int r = lin >> 5, kk = lin & 31;
            int kg = k0 + kk;
            Zs[r][kk] = (kg < 400) ? X[(size_t)(row0 + r) * F_IN + kg] : 0.f;
        }
#pragma unroll
        for (int p = 0; p < 16; ++p) {
            int lin = p * 256 + tid;
            int kr = lin >> 7, c = lin & 127;
            int kg = k0 + kr;
            Ws[kr][c] = (kg < 400) ? W[(size_t)kg * 128 + c] : 0.f;
        }
        __syncthreads();
#pragma unroll
        for (int kk = 0; kk < 32; ++kk) {
            float4 w = *(const float4*)&Ws[kk][tx * 4];
#pragma unroll
            for (int r = 0; r < 8; ++r) {
                float zz = Zs[ty * 8 + r][kk];
                acc[r][0] += zz * w.x;
                acc[r][1] += zz * w.y;
                acc[r][2] += zz * w.z;
                acc[r][3] += zz * w.w;
            }
        }
        __syncthreads();
    }

#pragma unroll
    for (int r = 0; r < 8; ++r) {
        int row = row0 + ty * 8 + r;
        int gv = gid[row];
        float g0 = ge[gv * 2], g1 = ge[gv * 2 + 1];
        float h0v = he[(row & 1) * 2], h1v = he[(row & 1) * 2 + 1];
        float4 o;
        int col = tx * 4;
        o.x = acc[r][0] + g0 * Wex[0][col+0] + g1 * Wex[1][col+0] + h0v * Wex[2][col+0] + h1v * Wex[3][col+0];
        o.y = acc[r][1] + g0 * Wex[0][col+1] + g1 * Wex[1][col+1] + h0v * Wex[2][col+1] + h1v * Wex[3][col+1];
        o.z = acc[r][2] + g0 * Wex[0][col+2] + g1 * Wex[1][col+2] + h0v * Wex[2][col+2] + h1v * Wex[3][col+2];
        o.w = acc[r][3] + g0 * Wex[0][col+3] + g1 * Wex[1][col+3] + h0v * Wex[2][col+3] + h1v * Wex[3][col+3];
        *(float4*)&T[(size_t)row * 128 + col] = o;
    }
}

// ---------------- plain GEMM K=128: T = H @ W  (no bias) ----------------

__global__ __launch_bounds__(256) void gemm_t(const float* __restrict__ H,
                                              const float* __restrict__ W,
                                              float* __restrict__ T) {
    __shared__ float Zs[64][33];
    __shared__ float Ws[32][128];
    int tid = threadIdx.x;
    int tx = tid & 31;
    int ty = tid >> 5;
    int row0 = blockIdx.x * 64;
    float acc[8][4];
#pragma unroll
    for (int r = 0; r < 8; ++r)
#pragma unroll
        for (int c = 0; c < 4; ++c) acc[r][c] = 0.f;

    for (int k0 = 0; k0 < 128; k0 += 32) {
#pragma unroll
        for (int p = 0; p < 8; ++p) {
            int lin = p * 256 + tid;
            int r = lin >> 5, kk = lin & 31;
            Zs[r][kk] = H[(size_t)(row0 + r) * 128 + k0 + kk];
        }
#pragma unroll
        for (int p = 0; p < 16; ++p) {
            int lin = p * 256 + tid;
            int kr = lin >> 7, c = lin & 127;
            Ws[kr][c] = W[(size_t)(k0 + kr) * 128 + c];
        }
        __syncthreads();
#pragma unroll
        for (int kk = 0; kk < 32; ++kk) {
            float4 w = *(const float4*)&Ws[kk][tx * 4];
#pragma unroll
            for (int r = 0; r < 8; ++r) {
                float zz = Zs[ty * 8 + r][kk];
                acc[r][0] += zz * w.x;
                acc[r][1] += zz * w.y;
                acc[r][2] += zz * w.z;
                acc[r][3] += zz * w.w;
            }
        }
        __syncthreads();
    }
#pragma unroll
    for (int r = 0; r < 8; ++r) {
        int row = row0 + ty * 8 + r;
        float4 o = {acc[r][0], acc[r][1], acc[r][2], acc[r][3]};
        *(float4*)&T[(size_t)row * 128 + tx * 4] = o;
    }
}

// ---------------- aggregation in projected space, LDS-staged ----------------
// z[i] = t[i] + sum_{src->i} t[src] + bias; fused per-block BN partial stats.
// grid = 64 graphs x 8 col-chunks(16) = 512 blocks, 256 threads (= 4 waves).
// Per wave: slot=lane>>4 (4 nodes in flight), lcol=lane&15 (16 cols).
// 4 waves x 4 slots = 16 nodes concurrently -> node stride 16.

__global__ __launch_bounds__(256) void aggregate_lds(const float* __restrict__ t,
                                                     const int* __restrict__ off,
                                                     const unsigned short* __restrict__ esrc16,
                                                     const float* __restrict__ bias,
                                                     float* __restrict__ z,
                                                     float* __restrict__ psum,
                                                     float* __restrict__ psq) {
    __shared__ float ts[NPG][17];
    __shared__ unsigned int es32[EPG / 2];
    __shared__ int offs[NPG + 1];
    __shared__ float sw[4][16], qw[4][16];

    int g = blockIdx.x >> 3;
    int chunk = blockIdx.x & 7;
    int c0 = chunk * 16;
    int tid = threadIdx.x;
    int node0 = g * NPG;
    int ebase = g * EPG;

    // stage feature slice [400 x 16]
    {
        int col = tid & 15;
        int r0 = tid >> 4;
        const float* tg = t + (size_t)node0 * 128 + c0;
        for (int r = r0; r < NPG; r += 16) ts[r][col] = tg[(size_t)r * 128 + col];
    }
    // stage edges (ushort local src) and offsets
    {
        const unsigned int* ep = (const unsigned int*)(esrc16 + (size_t)ebase);
        for (int i = tid; i < EPG / 2; i += 256) es32[i] = ep[i];
        for (int i = tid; i < NPG + 1; i += 256) offs[i] = off[node0 + i] - ebase;
    }
    __syncthreads();

    const unsigned short* es = (const unsigned short*)es32;
    int wave = tid >> 6;          // 0..3
    int lane = tid & 63;
    int slot = lane >> 4;         // 0..3
    int lcol = lane & 15;
    int col = c0 + lcol;
    float b = bias[col];
    float sacc = 0.f, qacc = 0.f;

    for (int d = wave * 4 + slot; d < NPG; d += 16) {
        int e0 = offs[d], e1 = offs[d + 1];
        float acc = ts[d][lcol];
        int e = e0;
        for (; e + 4 <= e1; e += 4) {
            int s0 = es[e], s1 = es[e + 1], s2 = es[e + 2], s3 = es[e + 3];
            acc += ts[s0][lcol];
            acc += ts[s1][lcol];
            acc += ts[s2][lcol];
            acc += ts[s3][lcol];
        }
        for (; e < e1; ++e) acc += ts[es[e]][lcol];
        float val = acc + b;
        z[(size_t)(node0 + d) * 128 + col] = val;
        sacc += val;
        qacc += val * val;
    }

    // reduce stats across the 4 slots within each wave (lane bits 4,5), then 4 waves via LDS
    sacc += __shfl_xor(sacc, 16);
    sacc += __shfl_xor(sacc, 32);
    qacc += __shfl_xor(qacc, 16);
    qacc += __shfl_xor(qacc, 32);
    if (lane < 16) { sw[wave][lcol] = sacc; qw[wave][lcol] = qacc; }
    __syncthreads();
    if (tid < 16) {
        float S = 0.f, Q = 0.f;
#pragma unroll
        for (int w = 0; w < 4; ++w) { S += sw[w][tid]; Q += qw[w][tid]; }
        psum[blockIdx.x * 16 + tid] = S;
        psq[blockIdx.x * 16 + tid] = Q;
    }
}

// ---------------- BN coefficients ----------------

__global__ __launch_bounds__(128) void bn_coef(const float* __restrict__ psum,
                                               const float* __restrict__ psq,
                                               const float* __restrict__ g,
                                               const float* __restrict__ be,
                                               float* __restrict__ coef) {
    int c = threadIdx.x;
    int chunk = c >> 4, lcol = c & 15;
    float S = 0.f, Q = 0.f;
    for (int gr = 0; gr < NB; ++gr) {
        int b = (gr * 8 + chunk) * 16 + lcol;
        S += psum[b];
        Q += psq[b];
    }
    float invn = 1.0f / (float)N_NODES;
    float mu = S * invn;
    float var = Q * invn - mu * mu;
    float a = g[c] * rsqrtf(var + BN_EPS);
    coef[c] = a;
    coef[128 + c] = be[c] - a * mu;
}

// ---------------- GEMM2: Hout = relu( relu(a*Z+c) @ W + b ) ----------------

__global__ __launch_bounds__(256) void gemm_relu(const float* __restrict__ Z,
                                                 const float* __restrict__ coef,
                                                 const float* __restrict__ W,
                                                 const float* __restrict__ bias,
                                                 float* __restrict__ Hout) {
    __shared__ float Zs[64][33];
    __shared__ float Ws[32][128];
    int tid = threadIdx.x;
    int tx = tid & 31;
    int ty = tid >> 5;
    int row0 = blockIdx.x * 64;
    float acc[8][4];
#pragma unroll
    for (int r = 0; r < 8; ++r)
#pragma unroll
        for (int c = 0; c < 4; ++c) acc[r][c] = 0.f;

    for (int k0 = 0; k0 < 128; k0 += 32) {
#pragma unroll
        for (int p = 0; p < 8; ++p) {
            int lin = p * 256 + tid;
            int r = lin >> 5, kk = lin & 31;
            int kg = k0 + kk;
            float raw = Z[(size_t)(row0 + r) * 128 + kg];
            Zs[r][kk] = fmaxf(coef[kg] * raw + coef[128 + kg], 0.f);
        }
#pragma unroll
        for (int p = 0; p < 16; ++p) {
            int lin = p * 256 + tid;
            int kr = lin >> 7, c = lin & 127;
            Ws[kr][c] = W[(size_t)(k0 + kr) * 128 + c];
        }
        __syncthreads();
#pragma unroll
        for (int kk = 0; kk < 32; ++kk) {
            float4 w = *(const float4*)&Ws[kk][tx * 4];
#pragma unroll
            for (int r = 0; r < 8; ++r) {
                float zz = Zs[ty * 8 + r][kk];
                acc[r][0] += zz * w.x;
                acc[r][1] += zz * w.y;
                acc[r][2] += zz * w.z;
                acc[r][3] += zz * w.w;
            }
        }
        __syncthreads();
    }

    float4 bv = *(const float4*)&bias[tx * 4];
#pragma unroll
    for (int r = 0; r < 8; ++r) {
        int row = row0 + ty * 8 + r;
        float4 o;
        o.x = fmaxf(acc[r][0] + bv.x, 0.f);
        o.y = fmaxf(acc[r][1] + bv.y, 0.f);
        o.z = fmaxf(acc[r][2] + bv.z, 0.f);
        o.w = fmaxf(acc[r][3] + bv.w, 0.f);
        *(float4*)&Hout[(size_t)row * 128 + tx * 4] = o;
    }
}

// ---------------- head ----------------

__global__ __launch_bounds__(128) void head(const float* __restrict__ h,
                                            const float* __restrict__ wfa,
                                            const float* __restrict__ bfa,
                                            const float* __restrict__ wfb,
                                            const float* __restrict__ bfb,
                                            float* __restrict__ out) {
    int g = blockIdx.x;
    int f = threadIdx.x;
    const float* hg = h + (size_t)g * NPG * 128;
    float pooled = 0.f;
    for (int n = 0; n < NPG; n += 4) {
        pooled += hg[(n + 0) * 128 + f];
        pooled += hg[(n + 1) * 128 + f];
        pooled += hg[(n + 2) * 128 + f];
        pooled += hg[(n + 3) * 128 + f];
    }
    __shared__ float pl[128];
    pl[f] = pooled;
    __syncthreads();
    float a = bfa[f];
    for (int k = 0; k < 128; ++k) a += pl[k] * wfa[k * 128 + f];
    float p2 = fmaxf(a, 0.f);
    __shared__ float o0[128], o1[128];
    o0[f] = p2 * wfb[f * 2 + 0];
    o1[f] = p2 * wfb[f * 2 + 1];
    __syncthreads();
    if (f == 0) {
        float a0 = bfb[0], a1 = bfb[1];
#pragma unroll
        for (int k = 0; k < 128; ++k) { a0 += o0[k]; a1 += o1[k]; }
        out[g * 2 + 0] = a0;
        out[g * 2 + 1] = a1;
    }
}

// ---------------- launch ----------------

extern "C" void kernel_launch(void* const* d_in, const int* in_sizes, int n_in,
                              void* d_out, int out_size, void* d_ws, size_t ws_size,
                              hipStream_t stream) {
    const float* x   = (const float*)d_in[0];
    const int* ei    = (const int*)d_in[1];
    const int* gid   = (const int*)d_in[3];
    const float* ge  = (const float*)d_in[4];
    const float* he  = (const float*)d_in[5];
    const float* wa[3] = {(const float*)d_in[6],  (const float*)d_in[12], (const float*)d_in[18]};
    const float* ba[3] = {(const float*)d_in[7],  (const float*)d_in[13], (const float*)d_in[19]};
    const float* gg[3] = {(const float*)d_in[8],  (const float*)d_in[14], (const float*)d_in[20]};
    const float* bb_[3]= {(const float*)d_in[9],  (const float*)d_in[15], (const float*)d_in[21]};
    const float* wb[3] = {(const float*)d_in[10], (const float*)d_in[16], (const float*)d_in[22]};
    const float* bbias[3] = {(const float*)d_in[11], (const float*)d_in[17], (const float*)d_in[23]};
    const float* wfa = (const float*)d_in[24];
    const float* bfa = (const float*)d_in[25];
    const float* wfb = (const float*)d_in[26];
    const float* bfb = (const float*)d_in[27];
    float* out = (float*)d_out;

    char* ws = (char*)d_ws;
    size_t o = 0;
    auto alloc = [&](size_t bytes) { char* p = ws + o; o += (bytes + 255) & ~(size_t)255; return p; };
    float* t    = (float*)alloc((size_t)N_NODES * 128 * 4);
    float* z    = (float*)alloc((size_t)N_NODES * 128 * 4);
    float* h    = (float*)alloc((size_t)N_NODES * 128 * 4);
    float* psum = (float*)alloc(512 * 16 * 4);
    float* psq  = (float*)alloc(512 * 16 * 4);
    float* coef = (float*)alloc(256 * 4);
    int* cnt    = (int*)alloc(N_NODES * 4);
    int* off    = (int*)alloc((N_NODES + 1) * 4);
    int* cur    = (int*)alloc(N_NODES * 4);
    unsigned short* esrc16 = (unsigned short*)alloc(NE * 2);
    (void)ws_size; (void)in_sizes; (void)n_in; (void)out_size;

    const int* esrc_in = ei;
    const int* edst_in = ei + NE;

    zero_i32<<<(N_NODES + 255) / 256, 256, 0, stream>>>(cnt, N_NODES);
    count_edges<<<(NE + 255) / 256, 256, 0, stream>>>(edst_in, cnt);
    scan_csr<<<1, 1024, 0, stream>>>(cnt, off, cur);
    scatter_edges<<<(NE + 255) / 256, 256, 0, stream>>>(esrc_in, edst_in, cur, esrc16);

    for (int L = 0; L < 3; ++L) {
        if (L == 0)
            gemm_embed<<<400, 256, 0, stream>>>(x, gid, ge, he, wa[0], t);
        else
            gemm_t<<<400, 256, 0, stream>>>(h, wa[L], t);
        aggregate_lds<<<512, 256, 0, stream>>>(t, off, esrc16, ba[L], z, psum, psq);
        bn_coef<<<1, 128, 0, stream>>>(psum, psq, gg[L], bb_[L], coef);
        gemm_relu<<<400, 256, 0, stream>>>(z, coef, wb[L], bbias[L], h);
    }

    head<<<NB, 128, 0, stream>>>(h, wfa, bfa, wfb, bfb, out);
}

// Round 5
// 444.998 us; speedup vs baseline: 1.7603x; 1.1520x over previous
//
#include <hip/hip_runtime.h>

#define N_NODES 25600
#define F_IN 400
#define NE 512000
#define NB 64
#define NPG 400
#define EPG 8000
#define BN_EPS 1e-5f

// ---------------- fused per-graph CSR build ----------------
// 64 blocks (1/graph), 256 threads. LDS histogram -> LDS Hillis-Steele scan ->
// LDS-atomic scatter. Writes graph-relative offsets goff[g][0..400] and
// local ushort src indices esrc16 (CSR by dst).

__global__ __launch_bounds__(256) void build_csr(const int* __restrict__ src,
                                                 const int* __restrict__ dst,
                                                 int* __restrict__ goff,
                                                 unsigned short* __restrict__ esrc16) {
    __shared__ unsigned short sloc[EPG];
    __shared__ unsigned short dloc[EPG];
    __shared__ int cnt[NPG];
    __shared__ int sa[512], sb[512];
    __shared__ int cur[NPG];
    int g = blockIdx.x;
    int tid = threadIdx.x;
    int ebase = g * EPG;
    int nbase = g * NPG;
    for (int i = tid; i < NPG; i += 256) cnt[i] = 0;
    __syncthreads();
    for (int e = tid; e < EPG; e += 256) {
        int s = src[ebase + e] - nbase;
        int d = dst[ebase + e] - nbase;
        sloc[e] = (unsigned short)s;
        dloc[e] = (unsigned short)d;
        atomicAdd(&cnt[d], 1);
    }
    __syncthreads();
    // inclusive scan over 512-padded bins (double-buffered Hillis-Steele, 9 rounds)
    for (int i = tid; i < 512; i += 256) sa[i] = (i < NPG) ? cnt[i] : 0;
    int* pin = sa;
    int* pout = sb;
    for (int d = 1; d < 512; d <<= 1) {
        __syncthreads();
        for (int i = tid; i < 512; i += 256)
            pout[i] = pin[i] + ((i >= d) ? pin[i - d] : 0);
        int* tswap = pin; pin = pout; pout = tswap;
    }
    __syncthreads();
    for (int i = tid; i < NPG; i += 256) cur[i] = (i == 0) ? 0 : pin[i - 1];
    for (int i = tid; i <= NPG; i += 256)
        goff[g * (NPG + 1) + i] = (i == 0) ? 0 : pin[i - 1];
    __syncthreads();
    for (int e = tid; e < EPG; e += 256) {
        int d = dloc[e];
        int pos = atomicAdd(&cur[d], 1);
        esrc16[ebase + pos] = sloc[e];
    }
}

// ---------------- GEMM layer0: T = [x | ge[gid] | he[i%2]] @ W0a (no bias) ----------------
// 32-row tiles -> 800 blocks. Zst = transposed A-tile [kk][row], stride 36 (16B aligned).

__global__ __launch_bounds__(256) void gemm_embed32(const float* __restrict__ X,
                                                    const int* __restrict__ gid,
                                                    const float* __restrict__ ge,
                                                    const float* __restrict__ he,
                                                    const float* __restrict__ W,
                                                    float* __restrict__ T) {
    __shared__ float Zst[32][36];
    __shared__ float Ws[32][128];
    __shared__ float Wex[4][128];
    int tid = threadIdx.x, tx = tid & 31, ty = tid >> 5;
    int row0 = blockIdx.x * 32;
    float acc[4][4] = {};

    for (int i = tid; i < 512; i += 256)
        Wex[i >> 7][i & 127] = W[(size_t)(400 + (i >> 7)) * 128 + (i & 127)];

    for (int k0 = 0; k0 < 400; k0 += 32) {
        {
            int r = tid >> 3, c4 = (tid & 7) * 4;
            int kg = k0 + c4;
            float v0, v1, v2, v3;
            if (kg + 3 < 400) {
                float4 v = *(const float4*)&X[(size_t)(row0 + r) * F_IN + kg];
                v0 = v.x; v1 = v.y; v2 = v.z; v3 = v.w;
            } else {
                const float* xr = X + (size_t)(row0 + r) * F_IN;
                v0 = (kg + 0 < 400) ? xr[kg + 0] : 0.f;
                v1 = (kg + 1 < 400) ? xr[kg + 1] : 0.f;
                v2 = (kg + 2 < 400) ? xr[kg + 2] : 0.f;
                v3 = (kg + 3 < 400) ? xr[kg + 3] : 0.f;
            }
            Zst[c4 + 0][r] = v0;
            Zst[c4 + 1][r] = v1;
            Zst[c4 + 2][r] = v2;
            Zst[c4 + 3][r] = v3;
        }
#pragma unroll
        for (int p = 0; p < 4; ++p) {
            int kr = (tid >> 5) + p * 8;
            int cb = (tid & 31) * 4;
            int kg = k0 + kr;
            float4 v = {0.f, 0.f, 0.f, 0.f};
            if (kg < 400) v = *(const float4*)&W[(size_t)kg * 128 + cb];
            *(float4*)&Ws[kr][cb] = v;
        }
        __syncthreads();
#pragma unroll
        for (int kk = 0; kk < 32; ++kk) {
            float4 w = *(const float4*)&Ws[kk][tx * 4];
            float4 za = *(const float4*)&Zst[kk][ty * 4];
            acc[0][0] += za.x * w.x; acc[0][1] += za.x * w.y; acc[0][2] += za.x * w.z; acc[0][3] += za.x * w.w;
            acc[1][0] += za.y * w.x; acc[1][1] += za.y * w.y; acc[1][2] += za.y * w.z; acc[1][3] += za.y * w.w;
            acc[2][0] += za.z * w.x; acc[2][1] += za.z * w.y; acc[2][2] += za.z * w.z; acc[2][3] += za.z * w.w;
            acc[3][0] += za.w * w.x; acc[3][1] += za.w * w.y; acc[3][2] += za.w * w.z; acc[3][3] += za.w * w.w;
        }
        __syncthreads();
    }

#pragma unroll
    for (int r = 0; r < 4; ++r) {
        int row = row0 + ty * 4 + r;
        int gv = gid[row];
        float g0 = ge[gv * 2], g1 = ge[gv * 2 + 1];
        float h0v = he[(row & 1) * 2], h1v = he[(row & 1) * 2 + 1];
        int col = tx * 4;
        float4 o;
        o.x = acc[r][0] + g0 * Wex[0][col + 0] + g1 * Wex[1][col + 0] + h0v * Wex[2][col + 0] + h1v * Wex[3][col + 0];
        o.y = acc[r][1] + g0 * Wex[0][col + 1] + g1 * Wex[1][col + 1] + h0v * Wex[2][col + 1] + h1v * Wex[3][col + 1];
        o.z = acc[r][2] + g0 * Wex[0][col + 2] + g1 * Wex[1][col + 2] + h0v * Wex[2][col + 2] + h1v * Wex[3][col + 2];
        o.w = acc[r][3] + g0 * Wex[0][col + 3] + g1 * Wex[1][col + 3] + h0v * Wex[2][col + 3] + h1v * Wex[3][col + 3];
        *(float4*)&T[(size_t)row * 128 + col] = o;
    }
}

// ---------------- plain GEMM K=128: T = H @ W (no bias), 32-row tiles ----------------

__global__ __launch_bounds__(256) void gemm_t32(const float* __restrict__ H,
                                                const float* __restrict__ W,
                                                float* __restrict__ T) {
    __shared__ float Zst[32][36];
    __shared__ float Ws[32][128];
    int tid = threadIdx.x, tx = tid & 31, ty = tid >> 5;
    int row0 = blockIdx.x * 32;
    float acc[4][4] = {};

    for (int k0 = 0; k0 < 128; k0 += 32) {
        {
            int r = tid >> 3, c4 = (tid & 7) * 4;
            float4 v = *(const float4*)&H[(size_t)(row0 + r) * 128 + k0 + c4];
            Zst[c4 + 0][r] = v.x;
            Zst[c4 + 1][r] = v.y;
            Zst[c4 + 2][r] = v.z;
            Zst[c4 + 3][r] = v.w;
        }
#pragma unroll
        for (int p = 0; p < 4; ++p) {
            int kr = (tid >> 5) + p * 8;
            int cb = (tid & 31) * 4;
            float4 v = *(const float4*)&W[(size_t)(k0 + kr) * 128 + cb];
            *(float4*)&Ws[kr][cb] = v;
        }
        __syncthreads();
#pragma unroll
        for (int kk = 0; kk < 32; ++kk) {
            float4 w = *(const float4*)&Ws[kk][tx * 4];
            float4 za = *(const float4*)&Zst[kk][ty * 4];
            acc[0][0] += za.x * w.x; acc[0][1] += za.x * w.y; acc[0][2] += za.x * w.z; acc[0][3] += za.x * w.w;
            acc[1][0] += za.y * w.x; acc[1][1] += za.y * w.y; acc[1][2] += za.y * w.z; acc[1][3] += za.y * w.w;
            acc[2][0] += za.z * w.x; acc[2][1] += za.z * w.y; acc[2][2] += za.z * w.z; acc[2][3] += za.z * w.w;
            acc[3][0] += za.w * w.x; acc[3][1] += za.w * w.y; acc[3][2] += za.w * w.z; acc[3][3] += za.w * w.w;
        }
        __syncthreads();
    }
#pragma unroll
    for (int r = 0; r < 4; ++r) {
        int row = row0 + ty * 4 + r;
        float4 o = {acc[r][0], acc[r][1], acc[r][2], acc[r][3]};
        *(float4*)&T[(size_t)row * 128 + tx * 4] = o;
    }
}

// ---------------- GEMM2: Hout = relu( relu(a*Z+c) @ W + b ), 32-row tiles ----------------

__global__ __launch_bounds__(256) void gemm_relu32(const float* __restrict__ Z,
                                                   const float* __restrict__ coef,
                                                   const float* __restrict__ W,
                                                   const float* __restrict__ bias,
                                                   float* __restrict__ Hout) {
    __shared__ float Zst[32][36];
    __shared__ float Ws[32][128];
    int tid = threadIdx.x, tx = tid & 31, ty = tid >> 5;
    int row0 = blockIdx.x * 32;
    float acc[4][4] = {};

    for (int k0 = 0; k0 < 128; k0 += 32) {
        {
            int r = tid >> 3, c4 = (tid & 7) * 4;
            int kg = k0 + c4;
            float4 v = *(const float4*)&Z[(size_t)(row0 + r) * 128 + kg];
            Zst[c4 + 0][r] = fmaxf(coef[kg + 0] * v.x + coef[128 + kg + 0], 0.f);
            Zst[c4 + 1][r] = fmaxf(coef[kg + 1] * v.y + coef[128 + kg + 1], 0.f);
            Zst[c4 + 2][r] = fmaxf(coef[kg + 2] * v.z + coef[128 + kg + 2], 0.f);
            Zst[c4 + 3][r] = fmaxf(coef[kg + 3] * v.w + coef[128 + kg + 3], 0.f);
        }
#pragma unroll
        for (int p = 0; p < 4; ++p) {
            int kr = (tid >> 5) + p * 8;
            int cb = (tid & 31) * 4;
            float4 v = *(const float4*)&W[(size_t)(k0 + kr) * 128 + cb];
            *(float4*)&Ws[kr][cb] = v;
        }
        __syncthreads();
#pragma unroll
        for (int kk = 0; kk < 32; ++kk) {
            float4 w = *(const float4*)&Ws[kk][tx * 4];
            float4 za = *(const float4*)&Zst[kk][ty * 4];
            acc[0][0] += za.x * w.x; acc[0][1] += za.x * w.y; acc[0][2] += za.x * w.z; acc[0][3] += za.x * w.w;
            acc[1][0] += za.y * w.x; acc[1][1] += za.y * w.y; acc[1][2] += za.y * w.z; acc[1][3] += za.y * w.w;
            acc[2][0] += za.z * w.x; acc[2][1] += za.z * w.y; acc[2][2] += za.z * w.z; acc[2][3] += za.z * w.w;
            acc[3][0] += za.w * w.x; acc[3][1] += za.w * w.y; acc[3][2] += za.w * w.z; acc[3][3] += za.w * w.w;
        }
        __syncthreads();
    }

    float4 bv = *(const float4*)&bias[tx * 4];
#pragma unroll
    for (int r = 0; r < 4; ++r) {
        int row = row0 + ty * 4 + r;
        float4 o;
        o.x = fmaxf(acc[r][0] + bv.x, 0.f);
        o.y = fmaxf(acc[r][1] + bv.y, 0.f);
        o.z = fmaxf(acc[r][2] + bv.z, 0.f);
        o.w = fmaxf(acc[r][3] + bv.w, 0.f);
        *(float4*)&Hout[(size_t)row * 128 + tx * 4] = o;
    }
}

// ---------------- aggregation in projected space, LDS-staged ----------------
// z[i] = t[i] + sum_{src->i} t[src] + bias; fused per-block BN partial stats.
// grid = 64 graphs x 8 col-chunks(16) = 512 blocks, 256 threads (= 4 waves).

__global__ __launch_bounds__(256) void aggregate_lds(const float* __restrict__ t,
                                                     const int* __restrict__ goff,
                                                     const unsigned short* __restrict__ esrc16,
                                                     const float* __restrict__ bias,
                                                     float* __restrict__ z,
                                                     float* __restrict__ psum,
                                                     float* __restrict__ psq) {
    __shared__ float ts[NPG][17];
    __shared__ unsigned int es32[EPG / 2];
    __shared__ int offs[NPG + 1];
    __shared__ float sw[4][16], qw[4][16];

    int g = blockIdx.x >> 3;
    int chunk = blockIdx.x & 7;
    int c0 = chunk * 16;
    int tid = threadIdx.x;
    int node0 = g * NPG;
    int ebase = g * EPG;

    {
        int col = tid & 15;
        int r0 = tid >> 4;
        const float* tg = t + (size_t)node0 * 128 + c0;
        for (int r = r0; r < NPG; r += 16) ts[r][col] = tg[(size_t)r * 128 + col];
    }
    {
        const unsigned int* ep = (const unsigned int*)(esrc16 + (size_t)ebase);
        for (int i = tid; i < EPG / 2; i += 256) es32[i] = ep[i];
        for (int i = tid; i < NPG + 1; i += 256) offs[i] = goff[g * (NPG + 1) + i];
    }
    __syncthreads();

    const unsigned short* es = (const unsigned short*)es32;
    int wave = tid >> 6;
    int lane = tid & 63;
    int slot = lane >> 4;
    int lcol = lane & 15;
    int col = c0 + lcol;
    float b = bias[col];
    float sacc = 0.f, qacc = 0.f;

    for (int d = wave * 4 + slot; d < NPG; d += 16) {
        int e0 = offs[d], e1 = offs[d + 1];
        float acc = ts[d][lcol];
        int e = e0;
        for (; e + 4 <= e1; e += 4) {
            int s0 = es[e], s1 = es[e + 1], s2 = es[e + 2], s3 = es[e + 3];
            acc += ts[s0][lcol];
            acc += ts[s1][lcol];
            acc += ts[s2][lcol];
            acc += ts[s3][lcol];
        }
        for (; e < e1; ++e) acc += ts[es[e]][lcol];
        float val = acc + b;
        z[(size_t)(node0 + d) * 128 + col] = val;
        sacc += val;
        qacc += val * val;
    }

    sacc += __shfl_xor(sacc, 16);
    sacc += __shfl_xor(sacc, 32);
    qacc += __shfl_xor(qacc, 16);
    qacc += __shfl_xor(qacc, 32);
    if (lane < 16) { sw[wave][lcol] = sacc; qw[wave][lcol] = qacc; }
    __syncthreads();
    if (tid < 16) {
        float S = 0.f, Q = 0.f;
#pragma unroll
        for (int w = 0; w < 4; ++w) { S += sw[w][tid]; Q += qw[w][tid]; }
        psum[blockIdx.x * 16 + tid] = S;
        psq[blockIdx.x * 16 + tid] = Q;
    }
}

// ---------------- BN coefficients ----------------

__global__ __launch_bounds__(128) void bn_coef(const float* __restrict__ psum,
                                               const float* __restrict__ psq,
                                               const float* __restrict__ g,
                                               const float* __restrict__ be,
                                               float* __restrict__ coef) {
    int c = threadIdx.x;
    int chunk = c >> 4, lcol = c & 15;
    float S = 0.f, Q = 0.f;
    for (int gr = 0; gr < NB; ++gr) {
        int b = (gr * 8 + chunk) * 16 + lcol;
        S += psum[b];
        Q += psq[b];
    }
    float invn = 1.0f / (float)N_NODES;
    float mu = S * invn;
    float var = Q * invn - mu * mu;
    float a = g[c] * rsqrtf(var + BN_EPS);
    coef[c] = a;
    coef[128 + c] = be[c] - a * mu;
}

// ---------------- head ----------------

__global__ __launch_bounds__(128) void head(const float* __restrict__ h,
                                            const float* __restrict__ wfa,
                                            const float* __restrict__ bfa,
                                            const float* __restrict__ wfb,
                                            const float* __restrict__ bfb,
                                            float* __restrict__ out) {
    int g = blockIdx.x;
    int f = threadIdx.x;
    const float* hg = h + (size_t)g * NPG * 128;
    float pooled = 0.f;
    for (int n = 0; n < NPG; n += 4) {
        pooled += hg[(n + 0) * 128 + f];
        pooled += hg[(n + 1) * 128 + f];
        pooled += hg[(n + 2) * 128 + f];
        pooled += hg[(n + 3) * 128 + f];
    }
    __shared__ float pl[128];
    pl[f] = pooled;
    __syncthreads();
    float a = bfa[f];
    for (int k = 0; k < 128; ++k) a += pl[k] * wfa[k * 128 + f];
    float p2 = fmaxf(a, 0.f);
    __shared__ float o0[128], o1[128];
    o0[f] = p2 * wfb[f * 2 + 0];
    o1[f] = p2 * wfb[f * 2 + 1];
    __syncthreads();
    if (f == 0) {
        float a0 = bfb[0], a1 = bfb[1];
#pragma unroll
        for (int k = 0; k < 128; ++k) { a0 += o0[k]; a1 += o1[k]; }
        out[g * 2 + 0] = a0;
        out[g * 2 + 1] = a1;
    }
}

// ---------------- launch ----------------

extern "C" void kernel_launch(void* const* d_in, const int* in_sizes, int n_in,
                              void* d_out, int out_size, void* d_ws, size_t ws_size,
                              hipStream_t stream) {
    const float* x   = (const float*)d_in[0];
    const int* ei    = (const int*)d_in[1];
    const int* gid   = (const int*)d_in[3];
    const float* ge  = (const float*)d_in[4];
    const float* he  = (const float*)d_in[5];
    const float* wa[3] = {(const float*)d_in[6],  (const float*)d_in[12], (const float*)d_in[18]};
    const float* ba[3] = {(const float*)d_in[7],  (const float*)d_in[13], (const float*)d_in[19]};
    const float* gg[3] = {(const float*)d_in[8],  (const float*)d_in[14], (const float*)d_in[20]};
    const float* bb_[3]= {(const float*)d_in[9],  (const float*)d_in[15], (const float*)d_in[21]};
    const float* wb[3] = {(const float*)d_in[10], (const float*)d_in[16], (const float*)d_in[22]};
    const float* bbias[3] = {(const float*)d_in[11], (const float*)d_in[17], (const float*)d_in[23]};
    const float* wfa = (const float*)d_in[24];
    const float* bfa = (const float*)d_in[25];
    const float* wfb = (const float*)d_in[26];
    const float* bfb = (const float*)d_in[27];
    float* out = (float*)d_out;

    char* ws = (char*)d_ws;
    size_t o = 0;
    auto alloc = [&](size_t bytes) { char* p = ws + o; o += (bytes + 255) & ~(size_t)255; return p; };
    float* t    = (float*)alloc((size_t)N_NODES * 128 * 4);
    float* z    = (float*)alloc((size_t)N_NODES * 128 * 4);
    float* h    = (float*)alloc((size_t)N_NODES * 128 * 4);
    float* psum = (float*)alloc(512 * 16 * 4);
    float* psq  = (float*)alloc(512 * 16 * 4);
    float* coef = (float*)alloc(256 * 4);
    int* goff   = (int*)alloc(NB * (NPG + 1) * 4);
    unsigned short* esrc16 = (unsigned short*)alloc(NE * 2);
    (void)ws_size; (void)in_sizes; (void)n_in; (void)out_size;

    const int* esrc_in = ei;
    const int* edst_in = ei + NE;

    build_csr<<<NB, 256, 0, stream>>>(esrc_in, edst_in, goff, esrc16);

    for (int L = 0; L < 3; ++L) {
        if (L == 0)
            gemm_embed32<<<800, 256, 0, stream>>>(x, gid, ge, he, wa[0], t);
        else
            gemm_t32<<<800, 256, 0, stream>>>(h, wa[L], t);
        aggregate_lds<<<512, 256, 0, stream>>>(t, goff, esrc16, ba[L], z, psum, psq);
        bn_coef<<<1, 128, 0, stream>>>(psum, psq, gg[L], bb_[L], coef);
        gemm_relu32<<<800, 256, 0, stream>>>(z, coef, wb[L], bbias[L], h);
    }

    head<<<NB, 128, 0, stream>>>(h, wfa, bfa, wfb, bfb, out);
}

// Round 6
// 378.689 us; speedup vs baseline: 2.0686x; 1.1751x over previous
//
#include <hip/hip_runtime.h>

#define N_NODES 25600
#define F_IN 400
#define NE 512000
#define NB 64
#define NPG 400
#define EPG 8000
#define BN_EPS 1e-5f

typedef __attribute__((ext_vector_type(8))) short short8;
typedef __attribute__((ext_vector_type(4))) float floatx4;

__device__ __forceinline__ unsigned short f2bf(float f) {
    unsigned int u = __float_as_uint(f);
    u += 0x7FFF + ((u >> 16) & 1);   // round-to-nearest-even
    return (unsigned short)(u >> 16);
}

// ---------------- fused per-graph CSR build ----------------

__global__ __launch_bounds__(256) void build_csr(const int* __restrict__ src,
                                                 const int* __restrict__ dst,
                                                 int* __restrict__ goff,
                                                 unsigned short* __restrict__ esrc16) {
    __shared__ unsigned short sloc[EPG];
    __shared__ unsigned short dloc[EPG];
    __shared__ int cnt[NPG];
    __shared__ int sa[512], sb[512];
    __shared__ int cur[NPG];
    int g = blockIdx.x;
    int tid = threadIdx.x;
    int ebase = g * EPG;
    int nbase = g * NPG;
    for (int i = tid; i < NPG; i += 256) cnt[i] = 0;
    __syncthreads();
    for (int e = tid; e < EPG; e += 256) {
        int s = src[ebase + e] - nbase;
        int d = dst[ebase + e] - nbase;
        sloc[e] = (unsigned short)s;
        dloc[e] = (unsigned short)d;
        atomicAdd(&cnt[d], 1);
    }
    __syncthreads();
    for (int i = tid; i < 512; i += 256) sa[i] = (i < NPG) ? cnt[i] : 0;
    int* pin = sa;
    int* pout = sb;
    for (int d = 1; d < 512; d <<= 1) {
        __syncthreads();
        for (int i = tid; i < 512; i += 256)
            pout[i] = pin[i] + ((i >= d) ? pin[i - d] : 0);
        int* tswap = pin; pin = pout; pout = tswap;
    }
    __syncthreads();
    for (int i = tid; i < NPG; i += 256) cur[i] = (i == 0) ? 0 : pin[i - 1];
    for (int i = tid; i <= NPG; i += 256)
        goff[g * (NPG + 1) + i] = (i == 0) ? 0 : pin[i - 1];
    __syncthreads();
    for (int e = tid; e < EPG; e += 256) {
        int d = dloc[e];
        int pos = atomicAdd(&cur[d], 1);
        esrc16[ebase + pos] = sloc[e];
    }
}

// ---------------- weight transpose + bf16 convert: Wt[n][k] = bf16(W[k][n]) ----------------

__global__ __launch_bounds__(256) void transpose_bf16(const float* __restrict__ src,
                                                      unsigned short* __restrict__ dst,
                                                      int K) {
    int idx = blockIdx.x * 256 + threadIdx.x;
    if (idx < 128 * K) {
        int n = idx / K, k = idx - n * K;
        dst[idx] = f2bf(src[(size_t)k * 128 + n]);
    }
}

// ---------------- MFMA GEMM: C[M x 128] = op(A[M x K]) @ Wt^T (+ epilogue) ----------------
// 64-row tiles, 256 threads = 4 waves; wave = 32 rows x 64 cols = 2x4 frags of 16x16.
// MODE 0 (embed): A = x (K=400), epilogue adds rank-4 fixup ge[gid]/he via W rows 400-403.
// MODE 1 (plain): C = A @ W.
// MODE 2 (bnrelu): staging applies relu(coef0*k + coef1); epilogue relu(acc + bias).

#define MODE_EMBED 0
#define MODE_PLAIN 1
#define MODE_BNRELU 2

template <int MODE, int K>
__global__ __launch_bounds__(256) void gemm_mfma(const float* __restrict__ A,
                                                 const unsigned short* __restrict__ Wt,
                                                 const float* __restrict__ Wfull,
                                                 const int* __restrict__ gid,
                                                 const float* __restrict__ ge,
                                                 const float* __restrict__ he,
                                                 const float* __restrict__ coef,
                                                 const float* __restrict__ bias,
                                                 float* __restrict__ C) {
    __shared__ __align__(16) unsigned short As[64][40];
    __shared__ __align__(16) unsigned short Bs[128][40];
    __shared__ float Wex[4][128];
    int tid = threadIdx.x;
    int m0 = blockIdx.x * 64;
    int wave = tid >> 6, lane = tid & 63;
    int wrow = (wave & 1) * 32;
    int wcol = (wave >> 1) * 64;

    if (MODE == MODE_EMBED) {
        for (int i = tid; i < 512; i += 256)
            Wex[i >> 7][i & 127] = Wfull[(size_t)(400 + (i >> 7)) * 128 + (i & 127)];
    }

    floatx4 acc[2][4];
#pragma unroll
    for (int rt = 0; rt < 2; ++rt)
#pragma unroll
        for (int ct = 0; ct < 4; ++ct) acc[rt][ct] = (floatx4){0.f, 0.f, 0.f, 0.f};

    const int KSTEPS = (K + 31) / 32;
    for (int ks = 0; ks < KSTEPS; ++ks) {
        int k0 = ks * 32;
        // ---- A staging: 64 rows x 32 k, fp32 -> bf16 ----
        {
            int r = tid >> 2, kc = (tid & 3) * 8;
            int kg = k0 + kc;
            short8 s;
            if ((K % 32 == 0) || (kg < K)) {
                const float* ar = A + (size_t)(m0 + r) * K + kg;
                float4 v0 = *(const float4*)ar;
                float4 v1 = *(const float4*)(ar + 4);
                float v[8] = {v0.x, v0.y, v0.z, v0.w, v1.x, v1.y, v1.z, v1.w};
                if (MODE == MODE_BNRELU) {
#pragma unroll
                    for (int j = 0; j < 8; ++j)
                        v[j] = fmaxf(coef[kg + j] * v[j] + coef[128 + kg + j], 0.f);
                }
#pragma unroll
                for (int j = 0; j < 8; ++j) s[j] = (short)f2bf(v[j]);
            } else {
#pragma unroll
                for (int j = 0; j < 8; ++j) s[j] = 0;
            }
            *(short8*)&As[r][kc] = s;
        }
        // ---- B staging: 128 cols x 32 k bf16 (already transposed) ----
        {
            int n = tid >> 1, kc = (tid & 1) * 16;
            int kg = k0 + kc;
            short8 b0, b1;
            if ((K % 32 == 0) || (kg < K)) {
                const unsigned short* wr = Wt + (size_t)n * K + kg;
                b0 = *(const short8*)wr;
                b1 = *(const short8*)(wr + 8);
            } else {
#pragma unroll
                for (int j = 0; j < 8; ++j) { b0[j] = 0; b1[j] = 0; }
            }
            *(short8*)&Bs[n][kc] = b0;
            *(short8*)&Bs[n][kc + 8] = b1;
        }
        __syncthreads();
        // ---- fragments + MFMA ----
        {
            int fm = lane & 15, quad = lane >> 4;
            short8 af[2], bf[4];
            af[0] = *(const short8*)&As[wrow + fm][quad * 8];
            af[1] = *(const short8*)&As[wrow + 16 + fm][quad * 8];
#pragma unroll
            for (int ct = 0; ct < 4; ++ct)
                bf[ct] = *(const short8*)&Bs[wcol + ct * 16 + fm][quad * 8];
#pragma unroll
            for (int rt = 0; rt < 2; ++rt)
#pragma unroll
                for (int ct = 0; ct < 4; ++ct)
                    acc[rt][ct] = __builtin_amdgcn_mfma_f32_16x16x32_bf16(
                        af[rt], bf[ct], acc[rt][ct], 0, 0, 0);
        }
        __syncthreads();
    }

    // ---- epilogue ----
    {
        int fm = lane & 15, quad = lane >> 4;
#pragma unroll
        for (int rt = 0; rt < 2; ++rt) {
#pragma unroll
            for (int ct = 0; ct < 4; ++ct) {
                int col = wcol + ct * 16 + fm;
#pragma unroll
                for (int r = 0; r < 4; ++r) {
                    int row = m0 + wrow + rt * 16 + quad * 4 + r;
                    float v = acc[rt][ct][r];
                    if (MODE == MODE_EMBED) {
                        int gv = gid[row];
                        float g0 = ge[gv * 2], g1 = ge[gv * 2 + 1];
                        float h0v = he[(row & 1) * 2], h1v = he[(row & 1) * 2 + 1];
                        v += g0 * Wex[0][col] + g1 * Wex[1][col] + h0v * Wex[2][col] + h1v * Wex[3][col];
                    }
                    if (MODE == MODE_BNRELU) {
                        v = fmaxf(v + bias[col], 0.f);
                    }
                    C[(size_t)row * 128 + col] = v;
                }
            }
        }
    }
}

// ---------------- aggregation in projected space, LDS-staged ----------------

__global__ __launch_bounds__(256) void aggregate_lds(const float* __restrict__ t,
                                                     const int* __restrict__ goff,
                                                     const unsigned short* __restrict__ esrc16,
                                                     const float* __restrict__ bias,
                                                     float* __restrict__ z,
                                                     float* __restrict__ psum,
                                                     float* __restrict__ psq) {
    __shared__ float ts[NPG][17];
    __shared__ unsigned int es32[EPG / 2];
    __shared__ int offs[NPG + 1];
    __shared__ float sw[4][16], qw[4][16];

    int g = blockIdx.x >> 3;
    int chunk = blockIdx.x & 7;
    int c0 = chunk * 16;
    int tid = threadIdx.x;
    int node0 = g * NPG;
    int ebase = g * EPG;

    {
        int col = tid & 15;
        int r0 = tid >> 4;
        const float* tg = t + (size_t)node0 * 128 + c0;
        for (int r = r0; r < NPG; r += 16) ts[r][col] = tg[(size_t)r * 128 + col];
    }
    {
        const unsigned int* ep = (const unsigned int*)(esrc16 + (size_t)ebase);
        for (int i = tid; i < EPG / 2; i += 256) es32[i] = ep[i];
        for (int i = tid; i < NPG + 1; i += 256) offs[i] = goff[g * (NPG + 1) + i];
    }
    __syncthreads();

    const unsigned short* es = (const unsigned short*)es32;
    int wave = tid >> 6;
    int lane = tid & 63;
    int slot = lane >> 4;
    int lcol = lane & 15;
    int col = c0 + lcol;
    float b = bias[col];
    float sacc = 0.f, qacc = 0.f;

    for (int d = wave * 4 + slot; d < NPG; d += 16) {
        int e0 = offs[d], e1 = offs[d + 1];
        float acc = ts[d][lcol];
        int e = e0;
        for (; e + 4 <= e1; e += 4) {
            int s0 = es[e], s1 = es[e + 1], s2 = es[e + 2], s3 = es[e + 3];
            acc += ts[s0][lcol];
            acc += ts[s1][lcol];
            acc += ts[s2][lcol];
            acc += ts[s3][lcol];
        }
        for (; e < e1; ++e) acc += ts[es[e]][lcol];
        float val = acc + b;
        z[(size_t)(node0 + d) * 128 + col] = val;
        sacc += val;
        qacc += val * val;
    }

    sacc += __shfl_xor(sacc, 16);
    sacc += __shfl_xor(sacc, 32);
    qacc += __shfl_xor(qacc, 16);
    qacc += __shfl_xor(qacc, 32);
    if (lane < 16) { sw[wave][lcol] = sacc; qw[wave][lcol] = qacc; }
    __syncthreads();
    if (tid < 16) {
        float S = 0.f, Q = 0.f;
#pragma unroll
        for (int w = 0; w < 4; ++w) { S += sw[w][tid]; Q += qw[w][tid]; }
        psum[blockIdx.x * 16 + tid] = S;
        psq[blockIdx.x * 16 + tid] = Q;
    }
}

// ---------------- BN coefficients ----------------

__global__ __launch_bounds__(128) void bn_coef(const float* __restrict__ psum,
                                               const float* __restrict__ psq,
                                               const float* __restrict__ g,
                                               const float* __restrict__ be,
                                               float* __restrict__ coef) {
    int c = threadIdx.x;
    int chunk = c >> 4, lcol = c & 15;
    float S = 0.f, Q = 0.f;
    for (int gr = 0; gr < NB; ++gr) {
        int b = (gr * 8 + chunk) * 16 + lcol;
        S += psum[b];
        Q += psq[b];
    }
    float invn = 1.0f / (float)N_NODES;
    float mu = S * invn;
    float var = Q * invn - mu * mu;
    float a = g[c] * rsqrtf(var + BN_EPS);
    coef[c] = a;
    coef[128 + c] = be[c] - a * mu;
}

// ---------------- head ----------------

__global__ __launch_bounds__(128) void head(const float* __restrict__ h,
                                            const float* __restrict__ wfa,
                                            const float* __restrict__ bfa,
                                            const float* __restrict__ wfb,
                                            const float* __restrict__ bfb,
                                            float* __restrict__ out) {
    int g = blockIdx.x;
    int f = threadIdx.x;
    const float* hg = h + (size_t)g * NPG * 128;
    float pooled = 0.f;
    for (int n = 0; n < NPG; n += 4) {
        pooled += hg[(n + 0) * 128 + f];
        pooled += hg[(n + 1) * 128 + f];
        pooled += hg[(n + 2) * 128 + f];
        pooled += hg[(n + 3) * 128 + f];
    }
    __shared__ float pl[128];
    pl[f] = pooled;
    __syncthreads();
    float a = bfa[f];
    for (int k = 0; k < 128; ++k) a += pl[k] * wfa[k * 128 + f];
    float p2 = fmaxf(a, 0.f);
    __shared__ float o0[128], o1[128];
    o0[f] = p2 * wfb[f * 2 + 0];
    o1[f] = p2 * wfb[f * 2 + 1];
    __syncthreads();
    if (f == 0) {
        float a0 = bfb[0], a1 = bfb[1];
#pragma unroll
        for (int k = 0; k < 128; ++k) { a0 += o0[k]; a1 += o1[k]; }
        out[g * 2 + 0] = a0;
        out[g * 2 + 1] = a1;
    }
}

// ---------------- launch ----------------

extern "C" void kernel_launch(void* const* d_in, const int* in_sizes, int n_in,
                              void* d_out, int out_size, void* d_ws, size_t ws_size,
                              hipStream_t stream) {
    const float* x   = (const float*)d_in[0];
    const int* ei    = (const int*)d_in[1];
    const int* gid   = (const int*)d_in[3];
    const float* ge  = (const float*)d_in[4];
    const float* he  = (const float*)d_in[5];
    const float* wa[3] = {(const float*)d_in[6],  (const float*)d_in[12], (const float*)d_in[18]};
    const float* ba[3] = {(const float*)d_in[7],  (const float*)d_in[13], (const float*)d_in[19]};
    const float* gg[3] = {(const float*)d_in[8],  (const float*)d_in[14], (const float*)d_in[20]};
    const float* bb_[3]= {(const float*)d_in[9],  (const float*)d_in[15], (const float*)d_in[21]};
    const float* wb[3] = {(const float*)d_in[10], (const float*)d_in[16], (const float*)d_in[22]};
    const float* bbias[3] = {(const float*)d_in[11], (const float*)d_in[17], (const float*)d_in[23]};
    const float* wfa = (const float*)d_in[24];
    const float* bfa = (const float*)d_in[25];
    const float* wfb = (const float*)d_in[26];
    const float* bfb = (const float*)d_in[27];
    float* out = (float*)d_out;

    char* ws = (char*)d_ws;
    size_t o = 0;
    auto alloc = [&](size_t bytes) { char* p = ws + o; o += (bytes + 255) & ~(size_t)255; return p; };
    float* t    = (float*)alloc((size_t)N_NODES * 128 * 4);
    float* z    = (float*)alloc((size_t)N_NODES * 128 * 4);
    float* h    = (float*)alloc((size_t)N_NODES * 128 * 4);
    float* psum = (float*)alloc(512 * 16 * 4);
    float* psq  = (float*)alloc(512 * 16 * 4);
    float* coef = (float*)alloc(256 * 4);
    int* goff   = (int*)alloc(NB * (NPG + 1) * 4);
    unsigned short* esrc16 = (unsigned short*)alloc(NE * 2);
    unsigned short* wt0 = (unsigned short*)alloc(128 * 400 * 2);
    unsigned short* wta1 = (unsigned short*)alloc(128 * 128 * 2);
    unsigned short* wta2 = (unsigned short*)alloc(128 * 128 * 2);
    unsigned short* wtb0 = (unsigned short*)alloc(128 * 128 * 2);
    unsigned short* wtb1 = (unsigned short*)alloc(128 * 128 * 2);
    unsigned short* wtb2 = (unsigned short*)alloc(128 * 128 * 2);
    unsigned short* wta[3] = {wt0, wta1, wta2};
    unsigned short* wtb[3] = {wtb0, wtb1, wtb2};
    (void)ws_size; (void)in_sizes; (void)n_in; (void)out_size;

    const int* esrc_in = ei;
    const int* edst_in = ei + NE;

    build_csr<<<NB, 256, 0, stream>>>(esrc_in, edst_in, goff, esrc16);
    transpose_bf16<<<200, 256, 0, stream>>>(wa[0], wt0, 400);
    transpose_bf16<<<64, 256, 0, stream>>>(wa[1], wta1, 128);
    transpose_bf16<<<64, 256, 0, stream>>>(wa[2], wta2, 128);
    transpose_bf16<<<64, 256, 0, stream>>>(wb[0], wtb0, 128);
    transpose_bf16<<<64, 256, 0, stream>>>(wb[1], wtb1, 128);
    transpose_bf16<<<64, 256, 0, stream>>>(wb[2], wtb2, 128);

    for (int L = 0; L < 3; ++L) {
        if (L == 0)
            gemm_mfma<MODE_EMBED, 400><<<400, 256, 0, stream>>>(
                x, wt0, wa[0], gid, ge, he, nullptr, nullptr, t);
        else
            gemm_mfma<MODE_PLAIN, 128><<<400, 256, 0, stream>>>(
                h, wta[L], nullptr, nullptr, nullptr, nullptr, nullptr, nullptr, t);
        aggregate_lds<<<512, 256, 0, stream>>>(t, goff, esrc16, ba[L], z, psum, psq);
        bn_coef<<<1, 128, 0, stream>>>(psum, psq, gg[L], bb_[L], coef);
        gemm_mfma<MODE_BNRELU, 128><<<400, 256, 0, stream>>>(
            z, wtb[L], nullptr, nullptr, nullptr, nullptr, coef, bbias[L], h);
    }

    head<<<NB, 128, 0, stream>>>(h, wfa, bfa, wfb, bfb, out);
}